// Round 5
// baseline (7931.113 us; speedup 1.0000x reference)
//
#include <hip/hip_runtime.h>
#include <stdint.h>

// Problem: B=8, L=4096, D=256, K=4096
#define NROWS 32768
#define KC 4096
#define DIM 256
#define BM 32            // rows per block
#define NCT 128          // col-tiles of 32 codes
#define NWV 8            // waves per block (512 threads)
#define TPW 16           // col-tiles per wave (8 waves x 16 = 128)
#define CAP 64           // raised from 40: em-only filter admits a few more cands
#define KAPPA 0.99960f   // exp(-margin), margin 4e-4 > validated 3e-4
#define K2L2E 2.88539008f // 2*log2(e)
#define L2E 1.44269504f

#define NCH1 ((TPW + 1) * 8)   // prime tile + 16 tiles, 8 chunks each = 136
#define NCH2 (TPW * 8)         // 128

#define OUT_IDX (NROWS * DIM)
#define OUT_SCAL (OUT_IDX + NROWS)

// Workspace layout (bytes)
#define WS_CNORM 0
#define WS_ZNORM 16384
#define WS_LOSS  147456
#define WS_AVGP8 147712                  // 8 shadows x 4096 f32 = 128 KB
#define WS_FRAG  278784                  // bf16 fragment image, 2 MB

typedef __bf16 bf8 __attribute__((ext_vector_type(8)));
typedef float f16v __attribute__((ext_vector_type(16)));

// async global->LDS, 16B per lane; LDS dest = wave-uniform base + lane*16
#define GLOAD_LDS(g, l) \
  __builtin_amdgcn_global_load_lds( \
      (const __attribute__((address_space(1))) void*)(g), \
      (__attribute__((address_space(3))) void*)(l), 16, 0, 0)

// monotonic float->uint order map (argmin with first-index tie-break)
__device__ __forceinline__ unsigned ford(float f) {
  unsigned u = __float_as_uint(f);
  return (u & 0x80000000u) ? ~u : (u | 0x80000000u);
}

// numpy pairwise-sum of x**2 (n=256), bitwise == np.sum(x**2) (validated R2-R6)
__device__ __forceinline__ float np_rownorm256(const float* __restrict__ p) {
  float h[2];
  #pragma unroll
  for (int half = 0; half < 2; ++half) {
    const float* b = p + half * 128;
    float r[8];
    #pragma unroll
    for (int j = 0; j < 8; ++j) { float v = b[j]; r[j] = __fmul_rn(v, v); }
    for (int i = 8; i < 128; i += 8) {
      #pragma unroll
      for (int j = 0; j < 8; ++j) {
        float v = b[i + j];
        r[j] = __fadd_rn(r[j], __fmul_rn(v, v));
      }
    }
    h[half] = __fadd_rn(
        __fadd_rn(__fadd_rn(r[0], r[1]), __fadd_rn(r[2], r[3])),
        __fadd_rn(__fadd_rn(r[4], r[5]), __fadd_rn(r[6], r[7])));
  }
  return __fadd_rn(h[0], h[1]);
}

__global__ void k_norms(const float* __restrict__ cbw, const float* __restrict__ z,
                        float* __restrict__ cnorm, float* __restrict__ znorm) {
  int r = blockIdx.x * 256 + threadIdx.x;
  if (r < KC) cnorm[r] = np_rownorm256(cbw + (size_t)r * DIM);
  else {
    int q = r - KC;
    if (q < NROWS) znorm[q] = np_rownorm256(z + (size_t)q * DIM);
  }
}

// Build bf16 B-fragment image: frag[ct][ds][lane][8] with
// frag(...)[j] = bf16(cb[ct*32 + (lane&31)][ds*16 + (lane>>5)*8 + j])
__global__ void k_frag(const float* __restrict__ cbw, __bf16* __restrict__ frag) {
  int idx = blockIdx.x * 256 + threadIdx.x;   // 131072 units of 16B
  int c = idx >> 5, u = idx & 31;
  int ds = u >> 1, half = u & 1;
  int ct = c >> 5, m = c & 31;
  int lane = half * 32 + m;
  const float* src = cbw + (size_t)c * DIM + ds * 16 + half * 8;
  float4 a = *(const float4*)src;
  float4 b = *(const float4*)(src + 4);
  bf8 h;
  h[0] = (__bf16)a.x; h[1] = (__bf16)a.y; h[2] = (__bf16)a.z; h[3] = (__bf16)a.w;
  h[4] = (__bf16)b.x; h[5] = (__bf16)b.y; h[6] = (__bf16)b.z; h[7] = (__bf16)b.w;
  *(bf8*)(frag + ((size_t)(ct * 16 + ds) * 64 + lane) * 8) = h;
}

// np-bitwise d2 (validated): sequential fmaf chain, d2 = fl(fl(rn+cn)-fl(2*mm))
__device__ __forceinline__ float exact_d2(const float* __restrict__ zr,
                                          const float* __restrict__ cr,
                                          float rn, float cn) {
  float mm = 0.f;
  for (int d = 0; d < DIM; d += 4) {
    float4 zv = *(const float4*)(zr + d);
    float4 cv = *(const float4*)(cr + d);
    mm = __builtin_fmaf(zv.x, cv.x, mm);
    mm = __builtin_fmaf(zv.y, cv.y, mm);
    mm = __builtin_fmaf(zv.z, cv.z, mm);
    mm = __builtin_fmaf(zv.w, cv.w, mm);
  }
  return __fsub_rn(__fadd_rn(rn, cn), __fmul_rn(2.f, mm));
}

// issue one 2KB chunk (2 ds-steps) of the B stream into ring slot nc&3.
// prime=1: stream tile 0 is the prime tile (ct=ctbase), tiles 1..16 -> ct=ctbase+tj-1
__device__ __forceinline__ void issue_chunk(const __bf16* __restrict__ frag,
                                            __bf16* ringw, int ctbase, int nc,
                                            int lane, int prime) {
  int tj = nc >> 3;
  int ct = ctbase + (prime ? (tj ? tj - 1 : 0) : tj);
  int slot = nc & 3;
  int ds0 = (nc & 7) * 2;
  const __bf16* g = frag + ((size_t)(ct * 16 + ds0)) * 512 + lane * 8;
  __bf16* l = ringw + slot * 1024;
  GLOAD_LDS(g, l);
  GLOAD_LDS(g + 512, l + 512);
}

// 512 threads, 8 waves, 1 block/CU (115 KB LDS). TLP (R4: stuck at ~14 waves/CU)
// is traded for a VGPR-free async B pipeline: per-wave 4-slot LDS ring fed by
// global_load_lds with counted vmcnt (R1-R3 proved register pipelines spill at
// the allocator's 64-84 VGPR budget).
__global__ __launch_bounds__(512, 2) void k_main(
    const float* __restrict__ z, const float* __restrict__ cbw,
    const float* __restrict__ cnorm, const float* __restrict__ znorm,
    const __bf16* __restrict__ frag, float* __restrict__ out,
    float* __restrict__ avgp8, double* __restrict__ losssum) {
  __shared__ __attribute__((aligned(16))) __bf16 Aimg[16 * 64 * 8];  // 16 KB
  __shared__ __attribute__((aligned(16))) __bf16 ring[NWV][4][1024]; // 64 KB
  __shared__ float cnormL[KC];                                       // 16 KB
  union CP { int cand[BM][CAP]; float pcol[KC]; }; // phase-disjoint alias, 16 KB
  __shared__ CP cp;
  __shared__ int ccount[BM];
  __shared__ unsigned rowmaxU[BM];                 // prime-seeded max of e
  __shared__ unsigned long long rowkey[BM];
  __shared__ float esumL[BM], invR[BM], lred[512];
  __shared__ int idxr[BM];

  const int t = threadIdx.x;
  const int lane = t & 63, wv = t >> 6;
  const int ln31 = lane & 31, lh = lane >> 5;
  const int row0 = blockIdx.x * BM;

  if (t < BM) {
    ccount[t] = 0; rowmaxU[t] = 0u; rowkey[t] = ~0ULL; esumL[t] = 0.f;
  }

  // ---- stage cnorm into LDS (keeps the sweep loops free of global loads) ----
  #pragma unroll
  for (int i = 0; i < 8; ++i) cnormL[t + 512 * i] = cnorm[t + 512 * i];

  // ---- stage A (rows 0..31) frag image into LDS cooperatively ----
  #pragma unroll
  for (int i = 0; i < 2; ++i) {
    int idx = t * 2 + i;              // 1024 units of 16B
    int l = idx & 63, ds = idx >> 6;
    int row = l & 31, d0 = ds * 16 + (l >> 5) * 8;
    const float* src = z + (size_t)(row0 + row) * DIM + d0;
    float4 a = *(const float4*)src;
    float4 b = *(const float4*)(src + 4);
    bf8 h;
    h[0] = (__bf16)a.x; h[1] = (__bf16)a.y; h[2] = (__bf16)a.z; h[3] = (__bf16)a.w;
    h[4] = (__bf16)b.x; h[5] = (__bf16)b.y; h[6] = (__bf16)b.z; h[7] = (__bf16)b.w;
    *(bf8*)&Aimg[((size_t)ds * 64 + l) * 8] = h;
  }
  __syncthreads();

  const int ctbase = wv * TPW;
  __bf16* ringw = &ring[wv][0][0];

  float es[16], em[16];
  #pragma unroll
  for (int i = 0; i < 16; ++i) { es[i] = 0.f; em[i] = 0.f; }

  // ============ Session 1: prime tile + phase-1 sweep (one linear ring) ======
  // Steady state: 3 chunks (6 loads) in flight; wait vmcnt(4) => chunk c landed.
  {
    asm volatile("s_waitcnt vmcnt(0)" ::: "memory");
    __builtin_amdgcn_sched_barrier(0);
    issue_chunk(frag, ringw, ctbase, 0, lane, 1);
    issue_chunk(frag, ringw, ctbase, 1, lane, 1);
    issue_chunk(frag, ringw, ctbase, 2, lane, 1);
    __builtin_amdgcn_sched_barrier(0);

    for (int ti = -1; ti < TPW; ++ti) {
      const int ct = ctbase + (ti < 0 ? 0 : ti);
      const float cnl = cnormL[ct * 32 + ln31] * L2E;
      const int base = (ti + 1) * 8;
      f16v acc;
      #pragma unroll
      for (int r = 0; r < 16; ++r) acc[r] = 0.f;
      #pragma unroll
      for (int s = 0; s < 8; ++s) {
        asm volatile("s_waitcnt vmcnt(4)" ::: "memory");
        __builtin_amdgcn_sched_barrier(0);
        const __bf16* bs = ringw + (s & 3) * 1024;
        bf8 B0 = *(const bf8*)(bs + lane * 8);
        bf8 B1 = *(const bf8*)(bs + 512 + lane * 8);
        bf8 A0 = *(const bf8*)&Aimg[((size_t)(s * 2) * 64 + lane) * 8];
        bf8 A1 = *(const bf8*)&Aimg[((size_t)(s * 2 + 1) * 64 + lane) * 8];
        acc = __builtin_amdgcn_mfma_f32_32x32x16_bf16(A0, B0, acc, 0, 0, 0);
        acc = __builtin_amdgcn_mfma_f32_32x32x16_bf16(A1, B1, acc, 0, 0, 0);
        int ni = base + s + 3; if (ni > NCH1 - 1) ni = NCH1 - 1;  // tail: dummy
        issue_chunk(frag, ringw, ctbase, ni, lane, 1);
        __builtin_amdgcn_sched_barrier(0);
      }
      if (ti < 0) {
        // prime epilogue: seed shared row max (all 8 waves x 32 cols = 256 cols)
        #pragma unroll
        for (int r = 0; r < 16; ++r) {
          const int row = (r & 3) + 8 * (r >> 2) + 4 * lh;
          float e = exp2f(__builtin_fmaf(acc[r], K2L2E, -cnl));
          atomicMax(&rowmaxU[row], __float_as_uint(e));  // e>0: order-preserving
        }
        __syncthreads();   // drains vmcnt; ring refills transparently after
        const float4* rmf = (const float4*)rowmaxU;
        float4 c0 = rmf[lh], c1 = rmf[2 + lh], c2 = rmf[4 + lh], c3 = rmf[6 + lh];
        em[0]  = c0.x; em[1]  = c0.y; em[2]  = c0.z; em[3]  = c0.w;
        em[4]  = c1.x; em[5]  = c1.y; em[6]  = c1.z; em[7]  = c1.w;
        em[8]  = c2.x; em[9]  = c2.y; em[10] = c2.z; em[11] = c2.w;
        em[12] = c3.x; em[13] = c3.y; em[14] = c3.z; em[15] = c3.w;
      } else {
        // branchless epilogue; em = running lower bound of row max (seeded).
        // Own record always fires its own cond -> candidate superset; exact
        // rescore unchanged (same validated argument as R4).
        unsigned cond = 0u;
        #pragma unroll
        for (int r = 0; r < 16; ++r) {
          float e = exp2f(__builtin_fmaf(acc[r], K2L2E, -cnl));
          es[r] += e;                       // same per-wave fl-chain order as R4
          cond |= (e >= em[r] * KAPPA) ? (1u << r) : 0u;
          em[r] = fmaxf(em[r], e);
        }
        if (cond) {
          #pragma unroll
          for (int r = 0; r < 16; ++r) {
            if (cond & (1u << r)) {
              const int row = (r & 3) + 8 * (r >> 2) + 4 * lh;
              int slot = atomicAdd(&ccount[row], 1);
              if (slot < CAP) cp.cand[row][slot] = ct * 32 + ln31;
            }
          }
        }
      }
    }
  }

  // ---- row exp-sum reduction (32 lanes of same half share rows) ----
  #pragma unroll
  for (int r = 0; r < 16; ++r) {
    float e = es[r];
    #pragma unroll
    for (int off = 16; off > 0; off >>= 1) e += __shfl_xor(e, off);
    if (ln31 == 0) {
      const int row = (r & 3) + 8 * (r >> 2) + 4 * lh;
      atomicAdd(&esumL[row], e);
    }
  }
  __syncthreads();
  if (t < BM) invR[t] = 1.0f / esumL[t];
  __syncthreads();

  // ---- exact np-bitwise rescore of candidates -> argmin (16 threads/row) ----
  {
    int r = t & 31, q = t >> 5;   // q in 0..15
    int cnt = ccount[r];
    const float* zr = z + (size_t)(row0 + r) * DIM;
    float rn = znorm[row0 + r];
    if (cnt <= CAP) {
      for (int s = q; s < cnt; s += 16) {
        int k = cp.cand[r][s];
        float d2 = exact_d2(zr, cbw + (size_t)k * DIM, rn, cnorm[k]);
        atomicMin(&rowkey[r], (((unsigned long long)ford(d2)) << 32) | (unsigned)k);
      }
    } else {  // overflow (improbable): full exact scan, still correct
      for (int k = q; k < KC; k += 16) {
        float d2 = exact_d2(zr, cbw + (size_t)k * DIM, rn, cnorm[k]);
        atomicMin(&rowkey[r], (((unsigned long long)ford(d2)) << 32) | (unsigned)k);
      }
    }
  }
  __syncthreads();
  if (t < BM) {
    int idx = (int)(rowkey[t] & 0xFFFFFFFFULL);
    idxr[t] = idx;
    out[OUT_IDX + row0 + t] = (float)idx;
  }
  __syncthreads();

  // ---- z_q gather, STE output, loss partial (512 threads: 2 rows at once) ----
  float lacc = 0.f;
  {
    const int col = t & 255;
    for (int r = (t >> 8); r < BM; r += 2) {
      int idx = idxr[r];
      float zq = cbw[(size_t)idx * DIM + col];
      float zv = z[(size_t)(row0 + r) * DIM + col];
      float df = __fsub_rn(zq, zv);
      out[(size_t)(row0 + r) * DIM + col] = __fadd_rn(zv, df);
      lacc += df * df;
    }
  }
  lred[t] = lacc;
  __syncthreads();
  #pragma unroll
  for (int s = 256; s > 0; s >>= 1) {
    if (t < s) lred[t] += lred[t + s];
    __syncthreads();
  }
  if (t == 0) atomicAdd(losssum, (double)lred[0]);

  // ---- invR to regs for phase 2 ----
  float ir[16];
  #pragma unroll
  for (int r = 0; r < 16; ++r)
    ir[r] = invR[(r & 3) + 8 * (r >> 2) + 4 * lh];
  __syncthreads();   // cand dead; pcol alias safe beyond here (drains vmcnt too)

  // ============ Session 2: phase-2 avg_probs sweep (same ring) ============
  {
    asm volatile("s_waitcnt vmcnt(0)" ::: "memory");
    __builtin_amdgcn_sched_barrier(0);
    issue_chunk(frag, ringw, ctbase, 0, lane, 0);
    issue_chunk(frag, ringw, ctbase, 1, lane, 0);
    issue_chunk(frag, ringw, ctbase, 2, lane, 0);
    __builtin_amdgcn_sched_barrier(0);

    for (int ti = 0; ti < TPW; ++ti) {
      const int ct = ctbase + ti;
      const float cnl = cnormL[ct * 32 + ln31] * L2E;
      const int base = ti * 8;
      f16v acc;
      #pragma unroll
      for (int r = 0; r < 16; ++r) acc[r] = 0.f;
      #pragma unroll
      for (int s = 0; s < 8; ++s) {
        asm volatile("s_waitcnt vmcnt(4)" ::: "memory");
        __builtin_amdgcn_sched_barrier(0);
        const __bf16* bs = ringw + (s & 3) * 1024;
        bf8 B0 = *(const bf8*)(bs + lane * 8);
        bf8 B1 = *(const bf8*)(bs + 512 + lane * 8);
        bf8 A0 = *(const bf8*)&Aimg[((size_t)(s * 2) * 64 + lane) * 8];
        bf8 A1 = *(const bf8*)&Aimg[((size_t)(s * 2 + 1) * 64 + lane) * 8];
        acc = __builtin_amdgcn_mfma_f32_32x32x16_bf16(A0, B0, acc, 0, 0, 0);
        acc = __builtin_amdgcn_mfma_f32_32x32x16_bf16(A1, B1, acc, 0, 0, 0);
        int ni = base + s + 3; if (ni > NCH2 - 1) ni = NCH2 - 1;  // tail: dummy
        issue_chunk(frag, ringw, ctbase, ni, lane, 0);
        __builtin_amdgcn_sched_barrier(0);
      }
      float s2 = 0.f;
      #pragma unroll
      for (int r = 0; r < 16; ++r) {
        float e = exp2f(__builtin_fmaf(acc[r], K2L2E, -cnl));
        s2 = __builtin_fmaf(e, ir[r], s2);
      }
      s2 += __shfl_xor(s2, 32);           // merge the two lh halves (same col)
      if (lh == 0) cp.pcol[ct * 32 + ln31] = s2;  // unique writer per col
    }
  }
  __syncthreads();
  {
    float* shadow = avgp8 + (size_t)(blockIdx.x & 7) * KC;
    #pragma unroll
    for (int i = 0; i < 8; ++i)
      atomicAdd(&shadow[t + 512 * i], cp.pcol[t + 512 * i]);
  }
}

__global__ void k_final(const float* __restrict__ avgp8,
                        const double* __restrict__ losssum,
                        float* __restrict__ out) {
  const int t = threadIdx.x;
  double part = 0.0;
  for (int k = t; k < KC; k += 256) {
    float a4 = 0.f;
    #pragma unroll
    for (int s = 0; s < 8; ++s) a4 += avgp8[s * KC + k];
    double a = (double)a4 / (double)NROWS;
    part += a * log(a + 1e-10);
  }
  __shared__ double sd[256];
  sd[t] = part;
  __syncthreads();
  for (int s = 128; s > 0; s >>= 1) {
    if (t < s) sd[t] += sd[t + s];
    __syncthreads();
  }
  if (t == 0) {
    double H = -sd[0];
    double mse = losssum[0] / (double)((size_t)NROWS * DIM);
    double ccl = 1.25 * mse;
    double sel = -0.1 * H;
    out[OUT_SCAL + 0] = (float)(ccl + sel);
    out[OUT_SCAL + 1] = (float)ccl;
    out[OUT_SCAL + 2] = (float)sel;
  }
}

extern "C" void kernel_launch(void* const* d_in, const int* in_sizes, int n_in,
                              void* d_out, int out_size, void* d_ws, size_t ws_size,
                              hipStream_t stream) {
  const float* z = (const float*)d_in[0];
  const float* cbw = (const float*)d_in[1];
  float* out = (float*)d_out;
  char* ws = (char*)d_ws;
  float* cnorm = (float*)(ws + WS_CNORM);
  float* znorm = (float*)(ws + WS_ZNORM);
  double* losssum = (double*)(ws + WS_LOSS);
  float* avgp8 = (float*)(ws + WS_AVGP8);
  __bf16* frag = (__bf16*)(ws + WS_FRAG);

  hipMemsetAsync(ws + WS_LOSS, 0, 8, stream);
  hipMemsetAsync(ws + WS_AVGP8, 0, 8 * KC * 4, stream);
  k_norms<<<(KC + NROWS) / 256, 256, 0, stream>>>(cbw, z, cnorm, znorm);
  k_frag<<<(KC * 32) / 256, 256, 0, stream>>>(cbw, frag);
  k_main<<<NROWS / BM, 512, 0, stream>>>(z, cbw, cnorm, znorm, frag, out,
                                         avgp8, losssum);
  k_final<<<1, 256, 0, stream>>>(avgp8, losssum, out);
}

// Round 6
// 582.650 us; speedup vs baseline: 13.6121x; 13.6121x over previous
//
#include <hip/hip_runtime.h>
#include <stdint.h>

// Problem: B=8, L=4096, D=256, K=4096
#define NROWS 32768
#define KC 4096
#define DIM 256
#define BM 32            // rows per block
#define NCT 128          // col-tiles of 32 codes
#define NWV 8            // waves per block (512 threads)
#define TPW 16           // col-tiles per wave (8 waves x 16 = 128)
#define CAP 40
#define KAPPA 0.99960f   // exp(-margin), margin 4e-4 > validated 3e-4
#define K2L2E 2.88539008f // 2*log2(e)
#define L2E 1.44269504f

#define OUT_IDX (NROWS * DIM)
#define OUT_SCAL (OUT_IDX + NROWS)

// Workspace layout (bytes)
#define WS_CNORM 0
#define WS_ZNORM 16384
#define WS_LOSS  147456
#define WS_AVGP8 147712                  // 8 shadows x 4096 f32 = 128 KB
#define WS_FRAG  278784                  // bf16 fragment image, 2 MB

typedef __bf16 bf8 __attribute__((ext_vector_type(8)));
typedef float f16v __attribute__((ext_vector_type(16)));

// async global->LDS, 16B per lane; LDS dest = wave-uniform base + lane*16
#define GLOAD_LDS(g, l) \
  __builtin_amdgcn_global_load_lds( \
      (const __attribute__((address_space(1))) void*)(g), \
      (__attribute__((address_space(3))) void*)(l), 16, 0, 0)

// monotonic float->uint order map (argmin with first-index tie-break)
__device__ __forceinline__ unsigned ford(float f) {
  unsigned u = __float_as_uint(f);
  return (u & 0x80000000u) ? ~u : (u | 0x80000000u);
}

// numpy pairwise-sum of x**2 (n=256), bitwise == np.sum(x**2) (validated R2-R6)
__device__ __forceinline__ float np_rownorm256(const float* __restrict__ p) {
  float h[2];
  #pragma unroll
  for (int half = 0; half < 2; ++half) {
    const float* b = p + half * 128;
    float r[8];
    #pragma unroll
    for (int j = 0; j < 8; ++j) { float v = b[j]; r[j] = __fmul_rn(v, v); }
    for (int i = 8; i < 128; i += 8) {
      #pragma unroll
      for (int j = 0; j < 8; ++j) {
        float v = b[i + j];
        r[j] = __fadd_rn(r[j], __fmul_rn(v, v));
      }
    }
    h[half] = __fadd_rn(
        __fadd_rn(__fadd_rn(r[0], r[1]), __fadd_rn(r[2], r[3])),
        __fadd_rn(__fadd_rn(r[4], r[5]), __fadd_rn(r[6], r[7])));
  }
  return __fadd_rn(h[0], h[1]);
}

__global__ void k_norms(const float* __restrict__ cbw, const float* __restrict__ z,
                        float* __restrict__ cnorm, float* __restrict__ znorm) {
  int r = blockIdx.x * 256 + threadIdx.x;
  if (r < KC) cnorm[r] = np_rownorm256(cbw + (size_t)r * DIM);
  else {
    int q = r - KC;
    if (q < NROWS) znorm[q] = np_rownorm256(z + (size_t)q * DIM);
  }
}

// Build bf16 B-fragment image: frag[ct][ds][lane][8] with
// frag(...)[j] = bf16(cb[ct*32 + (lane&31)][ds*16 + (lane>>5)*8 + j])
__global__ void k_frag(const float* __restrict__ cbw, __bf16* __restrict__ frag) {
  int idx = blockIdx.x * 256 + threadIdx.x;   // 131072 units of 16B
  int c = idx >> 5, u = idx & 31;
  int ds = u >> 1, half = u & 1;
  int ct = c >> 5, m = c & 31;
  int lane = half * 32 + m;
  const float* src = cbw + (size_t)c * DIM + ds * 16 + half * 8;
  float4 a = *(const float4*)src;
  float4 b = *(const float4*)(src + 4);
  bf8 h;
  h[0] = (__bf16)a.x; h[1] = (__bf16)a.y; h[2] = (__bf16)a.z; h[3] = (__bf16)a.w;
  h[4] = (__bf16)b.x; h[5] = (__bf16)b.y; h[6] = (__bf16)b.z; h[7] = (__bf16)b.w;
  *(bf8*)(frag + ((size_t)(ct * 16 + ds) * 64 + lane) * 8) = h;
}

// np-bitwise d2 (validated): sequential fmaf chain, d2 = fl(fl(rn+cn)-fl(2*mm))
__device__ __forceinline__ float exact_d2(const float* __restrict__ zr,
                                          const float* __restrict__ cr,
                                          float rn, float cn) {
  float mm = 0.f;
  for (int d = 0; d < DIM; d += 4) {
    float4 zv = *(const float4*)(zr + d);
    float4 cv = *(const float4*)(cr + d);
    mm = __builtin_fmaf(zv.x, cv.x, mm);
    mm = __builtin_fmaf(zv.y, cv.y, mm);
    mm = __builtin_fmaf(zv.z, cv.z, mm);
    mm = __builtin_fmaf(zv.w, cv.w, mm);
  }
  return __fsub_rn(__fadd_rn(rn, cn), __fmul_rn(2.f, mm));
}

// stage half h (ds h*8..h*8+7) of B tile ct into this wave's LDS buffer.
// 8 x global_load_lds of 1KB each; zero VGPR staging cost; drained by the
// compiler's vmcnt(0) at the next __syncthreads (m97-verified pattern).
__device__ __forceinline__ void stage_half(const __bf16* __restrict__ frag,
                                           __bf16* dst, int ct, int h, int lane) {
  const char* g = (const char*)frag + (size_t)ct * 16384 + (size_t)h * 8192
                  + (size_t)lane * 16;
  char* l = (char*)dst;
  #pragma unroll
  for (int c = 0; c < 8; ++c)
    GLOAD_LDS(g + c * 1024, l + c * 1024);
}

// 512 threads, 8 waves, 1 block/CU (155.5 KB LDS). R5 lesson: manual vmcnt +
// sched_barrier order-pinning is catastrophic; this uses the m97-verified
// schedule instead: [stage NEXT half via global_load_lds | compute CURRENT
// half from LDS | __syncthreads]. Double-buffered half-tiles per wave.
__global__ __launch_bounds__(512, 2) void k_main(
    const float* __restrict__ z, const float* __restrict__ cbw,
    const float* __restrict__ cnorm, const float* __restrict__ znorm,
    const __bf16* __restrict__ frag, float* __restrict__ out,
    float* __restrict__ avgp8, double* __restrict__ losssum) {
  __shared__ __attribute__((aligned(16))) __bf16 Aimg[16 * 64 * 8];   // 16 KB
  __shared__ __attribute__((aligned(16))) __bf16 Bst[2][NWV][4096];   // 128 KB
  __shared__ int cand[BM][CAP];                                       // 5 KB
  __shared__ int ccount[BM];
  __shared__ unsigned rowmaxU[BM];                 // running max of e (exp dom)
  __shared__ unsigned long long rowkey[BM];
  __shared__ float esumL[BM], invR[BM], lred[512];
  __shared__ int idxr[BM];

  const int t = threadIdx.x;
  const int lane = t & 63, wv = t >> 6;
  const int ln31 = lane & 31, lh = lane >> 5;
  const int row0 = blockIdx.x * BM;

  if (t < BM) {
    ccount[t] = 0; rowmaxU[t] = 0u; rowkey[t] = ~0ULL; esumL[t] = 0.f;
  }

  // ---- stage A (rows 0..31) frag image into LDS cooperatively ----
  #pragma unroll
  for (int i = 0; i < 2; ++i) {
    int idx = t * 2 + i;              // 1024 units of 16B
    int l = idx & 63, ds = idx >> 6;
    int row = l & 31, d0 = ds * 16 + (l >> 5) * 8;
    const float* src = z + (size_t)(row0 + row) * DIM + d0;
    float4 a = *(const float4*)src;
    float4 b = *(const float4*)(src + 4);
    bf8 h;
    h[0] = (__bf16)a.x; h[1] = (__bf16)a.y; h[2] = (__bf16)a.z; h[3] = (__bf16)a.w;
    h[4] = (__bf16)b.x; h[5] = (__bf16)b.y; h[6] = (__bf16)b.z; h[7] = (__bf16)b.w;
    *(bf8*)&Aimg[((size_t)ds * 64 + l) * 8] = h;
  }
  __syncthreads();

  const int ctbase = wv * TPW;

  float es[16];
  #pragma unroll
  for (int i = 0; i < 16; ++i) es[i] = 0.f;

#define CONSUME_HALF(bufptr, hh)                                              \
  {                                                                           \
    const __bf16* bs_ = (bufptr);                                             \
    _Pragma("unroll")                                                         \
    for (int c_ = 0; c_ < 8; ++c_) {                                          \
      bf8 Bf = *(const bf8*)(bs_ + c_ * 512 + lane * 8);                      \
      bf8 Af = *(const bf8*)&Aimg[((size_t)((hh) * 8 + c_) * 64 + lane) * 8]; \
      acc = __builtin_amdgcn_mfma_f32_32x32x16_bf16(Af, Bf, acc, 0, 0, 0);    \
    }                                                                         \
  }

  // ============ Phase 1: prime + sweep, 34 half-steps ============
  // Half-step stream: s=0,1 -> prime tile (ctbase h0,h1); s>=2 -> tile
  // ctbase+((s-2)>>1), half s&1 (prime tile re-staged at s=2,3 -> ti=0).
  // Per step: stage(s+1) into buf[(s+1)&1]; compute buf[s&1]; barrier.
  {
    stage_half(frag, &Bst[0][wv][0], ctbase, 0, lane);
    __syncthreads();

    float cr[16];
    f16v acc;
    for (int s = 0; s < 34; ++s) {
      {
        int sn = (s + 1 < 34) ? (s + 1) : 33;   // tail: harmless re-stage
        int ctn = ctbase + (sn < 2 ? 0 : ((sn - 2) >> 1));
        stage_half(frag, &Bst[(s + 1) & 1][wv][0], ctn, sn & 1, lane);
      }
      if ((s & 1) == 0) {
        #pragma unroll
        for (int r = 0; r < 16; ++r) acc[r] = 0.f;
        // tile-start refresh of shared row-max (lower bound -> superset filter)
        const float4* rmf = (const float4*)rowmaxU;
        float4 c0 = rmf[lh], c1 = rmf[2 + lh], c2 = rmf[4 + lh], c3 = rmf[6 + lh];
        cr[0]  = c0.x; cr[1]  = c0.y; cr[2]  = c0.z; cr[3]  = c0.w;
        cr[4]  = c1.x; cr[5]  = c1.y; cr[6]  = c1.z; cr[7]  = c1.w;
        cr[8]  = c2.x; cr[9]  = c2.y; cr[10] = c2.z; cr[11] = c2.w;
        cr[12] = c3.x; cr[13] = c3.y; cr[14] = c3.z; cr[15] = c3.w;
      }
      CONSUME_HALF(&Bst[s & 1][wv][0], s & 1)
      if (s & 1) {
        const int ct = (s == 1) ? ctbase : (ctbase + ((s - 2) >> 1));
        const float cnl = cnorm[ct * 32 + ln31] * L2E;
        if (s == 1) {
          // prime epilogue: seed shared row max (8 waves x 32 cols = 256 cols)
          #pragma unroll
          for (int r = 0; r < 16; ++r) {
            const int row = (r & 3) + 8 * (r >> 2) + 4 * lh;
            float e = exp2f(__builtin_fmaf(acc[r], K2L2E, -cnl));
            atomicMax(&rowmaxU[row], __float_as_uint(e));  // e>0: order-preserving
          }
        } else {
          // branchless epilogue: identical e/es math and order as R4 (absmax=0)
          unsigned cond = 0u;
          #pragma unroll
          for (int r = 0; r < 16; ++r) {
            float e = exp2f(__builtin_fmaf(acc[r], K2L2E, -cnl));
            es[r] += e;                       // same per-wave fl-chain order
            cond |= (e >= cr[r] * KAPPA) ? (1u << r) : 0u;
          }
          if (cond) {   // rare exec-masked slow path: refresh max + insert
            #pragma unroll
            for (int r = 0; r < 16; ++r) {
              if (cond & (1u << r)) {
                const int row = (r & 3) + 8 * (r >> 2) + 4 * lh;
                float e = exp2f(__builtin_fmaf(acc[r], K2L2E, -cnl));
                atomicMax(&rowmaxU[row], __float_as_uint(e));
                int slot = atomicAdd(&ccount[row], 1);
                if (slot < CAP) cand[row][slot] = ct * 32 + ln31;
              }
            }
          }
        }
      }
      __syncthreads();
    }
  }

  // ---- row exp-sum reduction (32 lanes of same half share rows) ----
  #pragma unroll
  for (int r = 0; r < 16; ++r) {
    float e = es[r];
    #pragma unroll
    for (int off = 16; off > 0; off >>= 1) e += __shfl_xor(e, off);
    if (ln31 == 0) {
      const int row = (r & 3) + 8 * (r >> 2) + 4 * lh;
      atomicAdd(&esumL[row], e);
    }
  }
  __syncthreads();
  if (t < BM) invR[t] = 1.0f / esumL[t];
  __syncthreads();

  // ---- exact np-bitwise rescore of candidates -> argmin (16 threads/row) ----
  {
    int r = t & 31, q = t >> 5;   // q in 0..15
    int cnt = ccount[r];
    const float* zr = z + (size_t)(row0 + r) * DIM;
    float rn = znorm[row0 + r];
    if (cnt <= CAP) {
      for (int s = q; s < cnt; s += 16) {
        int k = cand[r][s];
        float d2 = exact_d2(zr, cbw + (size_t)k * DIM, rn, cnorm[k]);
        atomicMin(&rowkey[r], (((unsigned long long)ford(d2)) << 32) | (unsigned)k);
      }
    } else {  // overflow (improbable): full exact scan, still correct
      for (int k = q; k < KC; k += 16) {
        float d2 = exact_d2(zr, cbw + (size_t)k * DIM, rn, cnorm[k]);
        atomicMin(&rowkey[r], (((unsigned long long)ford(d2)) << 32) | (unsigned)k);
      }
    }
  }
  __syncthreads();
  if (t < BM) {
    int idx = (int)(rowkey[t] & 0xFFFFFFFFULL);
    idxr[t] = idx;
    out[OUT_IDX + row0 + t] = (float)idx;
  }
  __syncthreads();

  // ---- z_q gather, STE output, loss partial (512 threads: 2 rows at once) ----
  float lacc = 0.f;
  {
    const int col = t & 255;
    for (int r = (t >> 8); r < BM; r += 2) {
      int idx = idxr[r];
      float zq = cbw[(size_t)idx * DIM + col];
      float zv = z[(size_t)(row0 + r) * DIM + col];
      float df = __fsub_rn(zq, zv);
      out[(size_t)(row0 + r) * DIM + col] = __fadd_rn(zv, df);
      lacc += df * df;
    }
  }
  lred[t] = lacc;
  __syncthreads();
  #pragma unroll
  for (int s = 256; s > 0; s >>= 1) {
    if (t < s) lred[t] += lred[t + s];
    __syncthreads();
  }
  if (t == 0) atomicAdd(losssum, (double)lred[0]);

  // ---- invR to regs for phase 2 ----
  float ir[16];
  #pragma unroll
  for (int r = 0; r < 16; ++r)
    ir[r] = invR[(r & 3) + 8 * (r >> 2) + 4 * lh];
  __syncthreads();

  // ============ Phase 2: avg_probs sweep, 32 half-steps ============
  // Same accumulation values as R4: one atomicAdd per (block, col) of the
  // same s2 (the pcol staging was only batching; numerics unchanged).
  {
    float* shadow = avgp8 + (size_t)(blockIdx.x & 7) * KC;
    stage_half(frag, &Bst[0][wv][0], ctbase, 0, lane);
    __syncthreads();
    f16v acc;
    for (int s = 0; s < 32; ++s) {
      {
        int sn = (s + 1 < 32) ? (s + 1) : 31;   // tail: harmless re-stage
        stage_half(frag, &Bst[(s + 1) & 1][wv][0], ctbase + (sn >> 1), sn & 1, lane);
      }
      if ((s & 1) == 0) {
        #pragma unroll
        for (int r = 0; r < 16; ++r) acc[r] = 0.f;
      }
      CONSUME_HALF(&Bst[s & 1][wv][0], s & 1)
      if (s & 1) {
        const int ct = ctbase + (s >> 1);
        const float cnl = cnorm[ct * 32 + ln31] * L2E;
        float s2 = 0.f;
        #pragma unroll
        for (int r = 0; r < 16; ++r) {
          float e = exp2f(__builtin_fmaf(acc[r], K2L2E, -cnl));
          s2 = __builtin_fmaf(e, ir[r], s2);
        }
        s2 += __shfl_xor(s2, 32);           // merge the two lh halves (same col)
        if (lh == 0) atomicAdd(&shadow[ct * 32 + ln31], s2);
      }
      __syncthreads();
    }
  }
}

__global__ void k_final(const float* __restrict__ avgp8,
                        const double* __restrict__ losssum,
                        float* __restrict__ out) {
  const int t = threadIdx.x;
  double part = 0.0;
  for (int k = t; k < KC; k += 256) {
    float a4 = 0.f;
    #pragma unroll
    for (int s = 0; s < 8; ++s) a4 += avgp8[s * KC + k];
    double a = (double)a4 / (double)NROWS;
    part += a * log(a + 1e-10);
  }
  __shared__ double sd[256];
  sd[t] = part;
  __syncthreads();
  for (int s = 128; s > 0; s >>= 1) {
    if (t < s) sd[t] += sd[t + s];
    __syncthreads();
  }
  if (t == 0) {
    double H = -sd[0];
    double mse = losssum[0] / (double)((size_t)NROWS * DIM);
    double ccl = 1.25 * mse;
    double sel = -0.1 * H;
    out[OUT_SCAL + 0] = (float)(ccl + sel);
    out[OUT_SCAL + 1] = (float)ccl;
    out[OUT_SCAL + 2] = (float)sel;
  }
}

extern "C" void kernel_launch(void* const* d_in, const int* in_sizes, int n_in,
                              void* d_out, int out_size, void* d_ws, size_t ws_size,
                              hipStream_t stream) {
  const float* z = (const float*)d_in[0];
  const float* cbw = (const float*)d_in[1];
  float* out = (float*)d_out;
  char* ws = (char*)d_ws;
  float* cnorm = (float*)(ws + WS_CNORM);
  float* znorm = (float*)(ws + WS_ZNORM);
  double* losssum = (double*)(ws + WS_LOSS);
  float* avgp8 = (float*)(ws + WS_AVGP8);
  __bf16* frag = (__bf16*)(ws + WS_FRAG);

  hipMemsetAsync(ws + WS_LOSS, 0, 8, stream);
  hipMemsetAsync(ws + WS_AVGP8, 0, 8 * KC * 4, stream);
  k_norms<<<(KC + NROWS) / 256, 256, 0, stream>>>(cbw, z, cnorm, znorm);
  k_frag<<<(KC * 32) / 256, 256, 0, stream>>>(cbw, frag);
  k_main<<<NROWS / BM, 512, 0, stream>>>(z, cbw, cnorm, znorm, frag, out,
                                         avgp8, losssum);
  k_final<<<1, 256, 0, stream>>>(avgp8, losssum, out);
}

// Round 7
// 454.166 us; speedup vs baseline: 17.4630x; 1.2829x over previous
//
#include <hip/hip_runtime.h>
#include <stdint.h>

// Problem: B=8, L=4096, D=256, K=4096
#define NROWS 32768
#define KC 4096
#define DIM 256
#define BM 128           // rows per block (4 row-tiles of 32)
#define NWV 8            // waves per block (512 threads): 4 row-tiles x 2 streams
#define TPS 64           // col-tiles per stream (2 streams x 64 = 128)
#define CAP 40
#define KAPPA 0.99960f   // exp(-margin), margin 4e-4 > validated 3e-4
#define K2L2E 2.88539008f // 2*log2(e)
#define L2E 1.44269504f

#define OUT_IDX (NROWS * DIM)
#define OUT_SCAL (OUT_IDX + NROWS)

// Workspace layout (bytes)
#define WS_CNORM 0
#define WS_ZNORM 16384
#define WS_LOSS  147456
#define WS_AVGP8 147712                  // 8 shadows x 4096 f32 = 128 KB
#define WS_FRAG  278784                  // bf16 fragment image, 2 MB

typedef __bf16 bf8 __attribute__((ext_vector_type(8)));
typedef float f16v __attribute__((ext_vector_type(16)));

// async global->LDS, 16B per lane; LDS dest = wave-uniform base + lane*16
#define GLOAD_LDS(g, l) \
  __builtin_amdgcn_global_load_lds( \
      (const __attribute__((address_space(1))) void*)(g), \
      (__attribute__((address_space(3))) void*)(l), 16, 0, 0)

// monotonic float->uint order map (argmin with first-index tie-break)
__device__ __forceinline__ unsigned ford(float f) {
  unsigned u = __float_as_uint(f);
  return (u & 0x80000000u) ? ~u : (u | 0x80000000u);
}

// numpy pairwise-sum of x**2 (n=256), bitwise == np.sum(x**2) (validated R2-R6)
__device__ __forceinline__ float np_rownorm256(const float* __restrict__ p) {
  float h[2];
  #pragma unroll
  for (int half = 0; half < 2; ++half) {
    const float* b = p + half * 128;
    float r[8];
    #pragma unroll
    for (int j = 0; j < 8; ++j) { float v = b[j]; r[j] = __fmul_rn(v, v); }
    for (int i = 8; i < 128; i += 8) {
      #pragma unroll
      for (int j = 0; j < 8; ++j) {
        float v = b[i + j];
        r[j] = __fadd_rn(r[j], __fmul_rn(v, v));
      }
    }
    h[half] = __fadd_rn(
        __fadd_rn(__fadd_rn(r[0], r[1]), __fadd_rn(r[2], r[3])),
        __fadd_rn(__fadd_rn(r[4], r[5]), __fadd_rn(r[6], r[7])));
  }
  return __fadd_rn(h[0], h[1]);
}

__global__ void k_norms(const float* __restrict__ cbw, const float* __restrict__ z,
                        float* __restrict__ cnorm, float* __restrict__ znorm) {
  int r = blockIdx.x * 256 + threadIdx.x;
  if (r < KC) cnorm[r] = np_rownorm256(cbw + (size_t)r * DIM);
  else {
    int q = r - KC;
    if (q < NROWS) znorm[q] = np_rownorm256(z + (size_t)q * DIM);
  }
}

// Build bf16 B-fragment image: frag[ct][ds][lane][8] with
// frag(...)[j] = bf16(cb[ct*32 + (lane&31)][ds*16 + (lane>>5)*8 + j])
__global__ void k_frag(const float* __restrict__ cbw, __bf16* __restrict__ frag) {
  int idx = blockIdx.x * 256 + threadIdx.x;   // 131072 units of 16B
  int c = idx >> 5, u = idx & 31;
  int ds = u >> 1, half = u & 1;
  int ct = c >> 5, m = c & 31;
  int lane = half * 32 + m;
  const float* src = cbw + (size_t)c * DIM + ds * 16 + half * 8;
  float4 a = *(const float4*)src;
  float4 b = *(const float4*)(src + 4);
  bf8 h;
  h[0] = (__bf16)a.x; h[1] = (__bf16)a.y; h[2] = (__bf16)a.z; h[3] = (__bf16)a.w;
  h[4] = (__bf16)b.x; h[5] = (__bf16)b.y; h[6] = (__bf16)b.z; h[7] = (__bf16)b.w;
  *(bf8*)(frag + ((size_t)(ct * 16 + ds) * 64 + lane) * 8) = h;
}

// np-bitwise d2 (validated): sequential fmaf chain, d2 = fl(fl(rn+cn)-fl(2*mm))
__device__ __forceinline__ float exact_d2(const float* __restrict__ zr,
                                          const float* __restrict__ cr,
                                          float rn, float cn) {
  float mm = 0.f;
  for (int d = 0; d < DIM; d += 4) {
    float4 zv = *(const float4*)(zr + d);
    float4 cv = *(const float4*)(cr + d);
    mm = __builtin_fmaf(zv.x, cv.x, mm);
    mm = __builtin_fmaf(zv.y, cv.y, mm);
    mm = __builtin_fmaf(zv.z, cv.z, mm);
    mm = __builtin_fmaf(zv.w, cv.w, mm);
  }
  return __fsub_rn(__fadd_rn(rn, cn), __fmul_rn(2.f, mm));
}

// B-tile load helper (LDS, bf16 elems)
#define BLD(bs, c) (*(const bf8*)((bs) + (c) * 512 + lane * 8))

// A-fragment registers: 16 named bf8 (64 VGPR), hoisted once per kernel
#define AQ_ALL(OP) OP(0) OP(1) OP(2) OP(3) OP(4) OP(5) OP(6) OP(7) \
                   OP(8) OP(9) OP(10) OP(11) OP(12) OP(13) OP(14) OP(15)
#define AQ_DECL(i) const bf8 aq##i = \
  *(const bf8*)&Aimg[((size_t)(wr * 16 + (i)) * 64 + lane) * 8];

#define MF(A, B) acc = __builtin_amdgcn_mfma_f32_32x32x16_bf16((A), (B), acc, 0, 0, 0);
#define CONSUME_H0(bs) { MF(aq0, BLD(bs,0)) MF(aq1, BLD(bs,1)) MF(aq2, BLD(bs,2)) \
  MF(aq3, BLD(bs,3)) MF(aq4, BLD(bs,4)) MF(aq5, BLD(bs,5)) MF(aq6, BLD(bs,6)) \
  MF(aq7, BLD(bs,7)) }
#define CONSUME_H1(bs) { MF(aq8, BLD(bs,0)) MF(aq9, BLD(bs,1)) MF(aq10, BLD(bs,2)) \
  MF(aq11, BLD(bs,3)) MF(aq12, BLD(bs,4)) MF(aq13, BLD(bs,5)) MF(aq14, BLD(bs,6)) \
  MF(aq15, BLD(bs,7)) }

// 512 threads, 8 waves, 1 block/CU (141 KB LDS). R4-R6 lesson: the binding
// constraint was redundant per-wave L2 B-traffic (~4.3 GB/launch at BM=32).
// BM=128 shares each staged B-tile across 4 row-waves (4x less L2 traffic),
// using the race-free R6 two-barrier/tile double-buffer schedule.
__global__ __launch_bounds__(512, 2) void k_main(
    const float* __restrict__ z, const float* __restrict__ cbw,
    const float* __restrict__ cnorm, const float* __restrict__ znorm,
    const __bf16* __restrict__ frag, float* __restrict__ out,
    float* __restrict__ avgp8, double* __restrict__ losssum) {
  __shared__ __attribute__((aligned(16))) __bf16 Aimg[4 * 16 * 64 * 8];  // 64 KB
  __shared__ __attribute__((aligned(16))) __bf16 Bst[2][2][4096];        // 32 KB
  __shared__ float cnormL[KC];                                           // 16 KB
  __shared__ int cand[BM][CAP];                                          // 20 KB
  __shared__ int ccount[BM];
  __shared__ unsigned rowmaxU[BM];                 // running max of e (exp dom)
  __shared__ unsigned long long rowkey[BM];
  __shared__ float esumL[BM], invR[BM], lred[512];
  __shared__ int idxr[BM];

  const int t = threadIdx.x;
  const int lane = t & 63, wv = t >> 6;
  const int ln31 = lane & 31, lh = lane >> 5;
  const int wr = wv & 3, wc = wv >> 2;    // row-tile, column-stream
  const int row0 = blockIdx.x * BM;
  const int ctbase = wc * TPS;

  if (t < BM) {
    ccount[t] = 0; rowmaxU[t] = 0u; rowkey[t] = ~0ULL; esumL[t] = 0.f;
  }

  // ---- stage cnorm into LDS ----
  #pragma unroll
  for (int i = 0; i < 8; ++i) cnormL[t + 512 * i] = cnorm[t + 512 * i];

  // ---- stage A (rows 0..127) frag image into LDS cooperatively ----
  #pragma unroll
  for (int i = 0; i < 8; ++i) {
    int idx = i * 512 + t;            // 4096 units of 16B
    int l = idx & 63, ds = (idx >> 6) & 15, rt = idx >> 10;
    int row = rt * 32 + (l & 31), d0 = ds * 16 + (l >> 5) * 8;
    const float* src = z + (size_t)(row0 + row) * DIM + d0;
    float4 a = *(const float4*)src;
    float4 b = *(const float4*)(src + 4);
    bf8 h;
    h[0] = (__bf16)a.x; h[1] = (__bf16)a.y; h[2] = (__bf16)a.z; h[3] = (__bf16)a.w;
    h[4] = (__bf16)b.x; h[5] = (__bf16)b.y; h[6] = (__bf16)b.z; h[7] = (__bf16)b.w;
    *(bf8*)&Aimg[((size_t)((rt * 16 + ds) * 64 + l)) * 8] = h;
  }
  __syncthreads();

  // ---- hoist A fragments to registers (64 VGPR; budget 256 at 1 block/CU) ----
  AQ_ALL(AQ_DECL)

  // stage one half (8KB) of B tile ct into Bst[buf][wc]: this wave issues its
  // 2KB share (2 x global_load_lds); 4 row-waves of the stream cover the half.
  #define STAGE2(ct, h, buf) { \
    const char* g_ = (const char*)frag + (size_t)(ct) * 16384 + (size_t)(h) * 8192 \
                     + wr * 2048 + (size_t)lane * 16; \
    char* l_ = (char*)Bst + (buf) * 16384 + wc * 8192 + wr * 2048; \
    GLOAD_LDS(g_, l_); \
    GLOAD_LDS(g_ + 1024, l_ + 1024); \
  }

  float es[16];
  #pragma unroll
  for (int i = 0; i < 16; ++i) es[i] = 0.f;

  // ============ Phase 1: prime tile (tt=0) + sweep (tt=1..64) ============
  // Per tile: [stage h1 -> buf1 | consume h0 from buf0 | barrier |
  //            stage next h0 -> buf0 | consume h1 | epilogue | barrier]
  {
    STAGE2(ctbase, 0, 0)
    __syncthreads();
    for (int tt = 0; tt < 65; ++tt) {
      const int ct = ctbase + (tt ? tt - 1 : 0);
      // --- half 0 ---
      STAGE2(ct, 1, 1)
      f16v acc;
      #pragma unroll
      for (int r = 0; r < 16; ++r) acc[r] = 0.f;
      // tile-start snapshot of shared row-max (lower bound -> superset filter)
      float cr[16];
      {
        const float4* rmf = (const float4*)(rowmaxU + wr * 32);
        float4 c0 = rmf[lh], c1 = rmf[2 + lh], c2 = rmf[4 + lh], c3 = rmf[6 + lh];
        cr[0]  = c0.x; cr[1]  = c0.y; cr[2]  = c0.z; cr[3]  = c0.w;
        cr[4]  = c1.x; cr[5]  = c1.y; cr[6]  = c1.z; cr[7]  = c1.w;
        cr[8]  = c2.x; cr[9]  = c2.y; cr[10] = c2.z; cr[11] = c2.w;
        cr[12] = c3.x; cr[13] = c3.y; cr[14] = c3.z; cr[15] = c3.w;
      }
      {
        const __bf16* bs = (const __bf16*)((const char*)Bst + 0 * 16384 + wc * 8192);
        CONSUME_H0(bs)
      }
      __syncthreads();
      // --- half 1 ---
      {
        int ctn = ctbase + ((tt < 64) ? tt : 63);   // tile tt+1 (tail: re-stage)
        STAGE2(ctn, 0, 0)
      }
      {
        const __bf16* bs = (const __bf16*)((const char*)Bst + 1 * 16384 + wc * 8192);
        CONSUME_H1(bs)
      }
      const float cnl = cnormL[ct * 32 + ln31] * L2E;
      if (tt == 0) {
        // prime epilogue: seed shared row max (2 streams x 4 row-waves cover all)
        #pragma unroll
        for (int r = 0; r < 16; ++r) {
          const int row = wr * 32 + (r & 3) + 8 * (r >> 2) + 4 * lh;
          float e = exp2f(__builtin_fmaf(acc[r], K2L2E, -cnl));
          atomicMax(&rowmaxU[row], __float_as_uint(e));  // e>0: order-preserving
        }
      } else {
        // branchless epilogue: identical e/es math and order as R4/R6 (absmax=0)
        unsigned cond = 0u;
        #pragma unroll
        for (int r = 0; r < 16; ++r) {
          float e = exp2f(__builtin_fmaf(acc[r], K2L2E, -cnl));
          es[r] += e;                       // per-wave sequential fl-chain
          cond |= (e >= cr[r] * KAPPA) ? (1u << r) : 0u;
        }
        if (cond) {   // rare exec-masked slow path: refresh max + insert
          #pragma unroll
          for (int r = 0; r < 16; ++r) {
            if (cond & (1u << r)) {
              const int row = wr * 32 + (r & 3) + 8 * (r >> 2) + 4 * lh;
              float e = exp2f(__builtin_fmaf(acc[r], K2L2E, -cnl));
              atomicMax(&rowmaxU[row], __float_as_uint(e));
              int slot = atomicAdd(&ccount[row], 1);
              if (slot < CAP) cand[row][slot] = ct * 32 + ln31;
            }
          }
        }
      }
      __syncthreads();
    }
  }

  // ---- row exp-sum reduction (32 lanes of same half share rows) ----
  #pragma unroll
  for (int r = 0; r < 16; ++r) {
    float e = es[r];
    #pragma unroll
    for (int off = 16; off > 0; off >>= 1) e += __shfl_xor(e, off);
    if (ln31 == 0) {
      const int row = wr * 32 + (r & 3) + 8 * (r >> 2) + 4 * lh;
      atomicAdd(&esumL[row], e);
    }
  }
  __syncthreads();
  if (t < BM) invR[t] = 1.0f / esumL[t];
  __syncthreads();

  // ---- exact np-bitwise rescore of candidates -> argmin (4 threads/row) ----
  {
    int r = t & 127, q = t >> 7;   // q in 0..3
    int cnt = ccount[r];
    const float* zr = z + (size_t)(row0 + r) * DIM;
    float rn = znorm[row0 + r];
    if (cnt <= CAP) {
      for (int s = q; s < cnt; s += 4) {
        int k = cand[r][s];
        float d2 = exact_d2(zr, cbw + (size_t)k * DIM, rn, cnormL[k]);
        atomicMin(&rowkey[r], (((unsigned long long)ford(d2)) << 32) | (unsigned)k);
      }
    } else {  // overflow (improbable): full exact scan, still correct
      for (int k = q; k < KC; k += 4) {
        float d2 = exact_d2(zr, cbw + (size_t)k * DIM, rn, cnormL[k]);
        atomicMin(&rowkey[r], (((unsigned long long)ford(d2)) << 32) | (unsigned)k);
      }
    }
  }
  __syncthreads();
  if (t < BM) {
    int idx = (int)(rowkey[t] & 0xFFFFFFFFULL);
    idxr[t] = idx;
    out[OUT_IDX + row0 + t] = (float)idx;
  }
  __syncthreads();

  // ---- z_q gather, STE output, loss partial (512 threads, 128 rows) ----
  float lacc = 0.f;
  {
    const int col = t & 255;
    for (int r = (t >> 8); r < BM; r += 2) {
      int idx = idxr[r];
      float zq = cbw[(size_t)idx * DIM + col];
      float zv = z[(size_t)(row0 + r) * DIM + col];
      float df = __fsub_rn(zq, zv);
      out[(size_t)(row0 + r) * DIM + col] = __fadd_rn(zv, df);
      lacc += df * df;
    }
  }
  lred[t] = lacc;
  __syncthreads();
  #pragma unroll
  for (int s = 256; s > 0; s >>= 1) {
    if (t < s) lred[t] += lred[t + s];
    __syncthreads();
  }
  if (t == 0) atomicAdd(losssum, (double)lred[0]);

  // ---- invR to regs for phase 2 ----
  float ir[16];
  #pragma unroll
  for (int r = 0; r < 16; ++r)
    ir[r] = invR[wr * 32 + (r & 3) + 8 * (r >> 2) + 4 * lh];
  __syncthreads();

  // ============ Phase 2: avg_probs sweep (tt = 0..63) ============
  {
    float* shadow = avgp8 + (size_t)(blockIdx.x & 7) * KC;
    STAGE2(ctbase, 0, 0)
    __syncthreads();
    for (int tt = 0; tt < 64; ++tt) {
      const int ct = ctbase + tt;
      STAGE2(ct, 1, 1)
      f16v acc;
      #pragma unroll
      for (int r = 0; r < 16; ++r) acc[r] = 0.f;
      {
        const __bf16* bs = (const __bf16*)((const char*)Bst + 0 * 16384 + wc * 8192);
        CONSUME_H0(bs)
      }
      __syncthreads();
      {
        int ctn = ctbase + ((tt < 63) ? tt + 1 : 63);
        STAGE2(ctn, 0, 0)
      }
      {
        const __bf16* bs = (const __bf16*)((const char*)Bst + 1 * 16384 + wc * 8192);
        CONSUME_H1(bs)
      }
      const float cnl = cnormL[ct * 32 + ln31] * L2E;
      float s2 = 0.f;
      #pragma unroll
      for (int r = 0; r < 16; ++r) {
        float e = exp2f(__builtin_fmaf(acc[r], K2L2E, -cnl));
        s2 = __builtin_fmaf(e, ir[r], s2);
      }
      s2 += __shfl_xor(s2, 32);           // merge the two lh halves (same col)
      if (lh == 0) atomicAdd(&shadow[ct * 32 + ln31], s2);  // 4 row-waves/col
      __syncthreads();
    }
  }
}

__global__ void k_final(const float* __restrict__ avgp8,
                        const double* __restrict__ losssum,
                        float* __restrict__ out) {
  const int t = threadIdx.x;
  double part = 0.0;
  for (int k = t; k < KC; k += 256) {
    float a4 = 0.f;
    #pragma unroll
    for (int s = 0; s < 8; ++s) a4 += avgp8[s * KC + k];
    double a = (double)a4 / (double)NROWS;
    part += a * log(a + 1e-10);
  }
  __shared__ double sd[256];
  sd[t] = part;
  __syncthreads();
  for (int s = 128; s > 0; s >>= 1) {
    if (t < s) sd[t] += sd[t + s];
    __syncthreads();
  }
  if (t == 0) {
    double H = -sd[0];
    double mse = losssum[0] / (double)((size_t)NROWS * DIM);
    double ccl = 1.25 * mse;
    double sel = -0.1 * H;
    out[OUT_SCAL + 0] = (float)(ccl + sel);
    out[OUT_SCAL + 1] = (float)ccl;
    out[OUT_SCAL + 2] = (float)sel;
  }
}

extern "C" void kernel_launch(void* const* d_in, const int* in_sizes, int n_in,
                              void* d_out, int out_size, void* d_ws, size_t ws_size,
                              hipStream_t stream) {
  const float* z = (const float*)d_in[0];
  const float* cbw = (const float*)d_in[1];
  float* out = (float*)d_out;
  char* ws = (char*)d_ws;
  float* cnorm = (float*)(ws + WS_CNORM);
  float* znorm = (float*)(ws + WS_ZNORM);
  double* losssum = (double*)(ws + WS_LOSS);
  float* avgp8 = (float*)(ws + WS_AVGP8);
  __bf16* frag = (__bf16*)(ws + WS_FRAG);

  hipMemsetAsync(ws + WS_LOSS, 0, 8, stream);
  hipMemsetAsync(ws + WS_AVGP8, 0, 8 * KC * 4, stream);
  k_norms<<<(KC + NROWS) / 256, 256, 0, stream>>>(cbw, z, cnorm, znorm);
  k_frag<<<(KC * 32) / 256, 256, 0, stream>>>(cbw, frag);
  k_main<<<NROWS / BM, 512, 0, stream>>>(z, cbw, cnorm, znorm, frag, out,
                                         avgp8, losssum);
  k_final<<<1, 256, 0, stream>>>(avgp8, losssum, out);
}

// Round 8
// 439.346 us; speedup vs baseline: 18.0521x; 1.0337x over previous
//
#include <hip/hip_runtime.h>
#include <stdint.h>

// Problem: B=8, L=4096, D=256, K=4096
#define NROWS 32768
#define KC 4096
#define DIM 256
#define BM 64            // rows per block (2 row-tiles of 32)
#define NWV 4            // waves per block (256 threads): 2 row-tiles x 2 streams
#define TPS 64           // col-tiles per stream (2 streams x 64 = 128)
#define CAP 40
#define KAPPA 0.99960f   // exp(-margin), margin 4e-4 > validated 3e-4
#define K2L2E 2.88539008f // 2*log2(e)
#define L2E 1.44269504f

#define OUT_IDX (NROWS * DIM)
#define OUT_SCAL (OUT_IDX + NROWS)

// Workspace layout (bytes)
#define WS_CNORM 0
#define WS_ZNORM 16384
#define WS_LOSS  147456
#define WS_AVGP8 147712                  // 8 shadows x 4096 f32 = 128 KB
#define WS_FRAG  278784                  // bf16 fragment image, 2 MB

typedef __bf16 bf8 __attribute__((ext_vector_type(8)));
typedef float f16v __attribute__((ext_vector_type(16)));

// async global->LDS, 16B per lane; LDS dest = wave-uniform base + lane*16
#define GLOAD_LDS(g, l) \
  __builtin_amdgcn_global_load_lds( \
      (const __attribute__((address_space(1))) void*)(g), \
      (__attribute__((address_space(3))) void*)(l), 16, 0, 0)

// monotonic float->uint order map (argmin with first-index tie-break)
__device__ __forceinline__ unsigned ford(float f) {
  unsigned u = __float_as_uint(f);
  return (u & 0x80000000u) ? ~u : (u | 0x80000000u);
}

// numpy pairwise-sum of x**2 (n=256), bitwise == np.sum(x**2) (validated R2-R6)
__device__ __forceinline__ float np_rownorm256(const float* __restrict__ p) {
  float h[2];
  #pragma unroll
  for (int half = 0; half < 2; ++half) {
    const float* b = p + half * 128;
    float r[8];
    #pragma unroll
    for (int j = 0; j < 8; ++j) { float v = b[j]; r[j] = __fmul_rn(v, v); }
    for (int i = 8; i < 128; i += 8) {
      #pragma unroll
      for (int j = 0; j < 8; ++j) {
        float v = b[i + j];
        r[j] = __fadd_rn(r[j], __fmul_rn(v, v));
      }
    }
    h[half] = __fadd_rn(
        __fadd_rn(__fadd_rn(r[0], r[1]), __fadd_rn(r[2], r[3])),
        __fadd_rn(__fadd_rn(r[4], r[5]), __fadd_rn(r[6], r[7])));
  }
  return __fadd_rn(h[0], h[1]);
}

__global__ void k_norms(const float* __restrict__ cbw, const float* __restrict__ z,
                        float* __restrict__ cnorm, float* __restrict__ znorm) {
  int r = blockIdx.x * 256 + threadIdx.x;
  if (r < KC) cnorm[r] = np_rownorm256(cbw + (size_t)r * DIM);
  else {
    int q = r - KC;
    if (q < NROWS) znorm[q] = np_rownorm256(z + (size_t)q * DIM);
  }
}

// Build bf16 B-fragment image: frag[ct][ds][lane][8] with
// frag(...)[j] = bf16(cb[ct*32 + (lane&31)][ds*16 + (lane>>5)*8 + j])
__global__ void k_frag(const float* __restrict__ cbw, __bf16* __restrict__ frag) {
  int idx = blockIdx.x * 256 + threadIdx.x;   // 131072 units of 16B
  int c = idx >> 5, u = idx & 31;
  int ds = u >> 1, half = u & 1;
  int ct = c >> 5, m = c & 31;
  int lane = half * 32 + m;
  const float* src = cbw + (size_t)c * DIM + ds * 16 + half * 8;
  float4 a = *(const float4*)src;
  float4 b = *(const float4*)(src + 4);
  bf8 h;
  h[0] = (__bf16)a.x; h[1] = (__bf16)a.y; h[2] = (__bf16)a.z; h[3] = (__bf16)a.w;
  h[4] = (__bf16)b.x; h[5] = (__bf16)b.y; h[6] = (__bf16)b.z; h[7] = (__bf16)b.w;
  *(bf8*)(frag + ((size_t)(ct * 16 + ds) * 64 + lane) * 8) = h;
}

// np-bitwise d2 (validated): sequential fmaf chain, d2 = fl(fl(rn+cn)-fl(2*mm))
__device__ __forceinline__ float exact_d2(const float* __restrict__ zr,
                                          const float* __restrict__ cr,
                                          float rn, float cn) {
  float mm = 0.f;
  for (int d = 0; d < DIM; d += 4) {
    float4 zv = *(const float4*)(zr + d);
    float4 cv = *(const float4*)(cr + d);
    mm = __builtin_fmaf(zv.x, cv.x, mm);
    mm = __builtin_fmaf(zv.y, cv.y, mm);
    mm = __builtin_fmaf(zv.z, cv.z, mm);
    mm = __builtin_fmaf(zv.w, cv.w, mm);
  }
  return __fsub_rn(__fadd_rn(rn, cn), __fmul_rn(2.f, mm));
}

// B-tile load helper (LDS, bf16 elems)
#define BLD(bs, c) (*(const bf8*)((bs) + (c) * 512 + lane * 8))

// A-fragment registers: 16 named bf8 (64 VGPR), hoisted once per kernel
#define AQ_ALL(OP) OP(0) OP(1) OP(2) OP(3) OP(4) OP(5) OP(6) OP(7) \
                   OP(8) OP(9) OP(10) OP(11) OP(12) OP(13) OP(14) OP(15)
#define AQ_DECL(i) const bf8 aq##i = \
  *(const bf8*)&U[((size_t)(wr * 16 + (i)) * 64 + lane) * 8];

#define MF(A, B) acc = __builtin_amdgcn_mfma_f32_32x32x16_bf16((A), (B), acc, 0, 0, 0);
#define CONSUME_H0(bs) { MF(aq0, BLD(bs,0)) MF(aq1, BLD(bs,1)) MF(aq2, BLD(bs,2)) \
  MF(aq3, BLD(bs,3)) MF(aq4, BLD(bs,4)) MF(aq5, BLD(bs,5)) MF(aq6, BLD(bs,6)) \
  MF(aq7, BLD(bs,7)) }
#define CONSUME_H1(bs) { MF(aq8, BLD(bs,0)) MF(aq9, BLD(bs,1)) MF(aq10, BLD(bs,2)) \
  MF(aq11, BLD(bs,3)) MF(aq12, BLD(bs,4)) MF(aq13, BLD(bs,5)) MF(aq14, BLD(bs,6)) \
  MF(aq15, BLD(bs,7)) }

// 256 threads, 4 waves, ~46 KB LDS -> 2 independent blocks/CU (grid 512 = 2/CU).
// R0/R4/R7 all plateaued ~380-400 us with ONE barrier group per CU; m97/m114
// evidence: barrier-drain stalls are hidden only by OTHER blocks' waves. The
// A-stage LDS is reused as the B double-buffers after hoisting A to registers.
__global__ __launch_bounds__(256, 2) void k_main(
    const float* __restrict__ z, const float* __restrict__ cbw,
    const float* __restrict__ cnorm, const float* __restrict__ znorm,
    const __bf16* __restrict__ frag, float* __restrict__ out,
    float* __restrict__ avgp8, double* __restrict__ losssum) {
  // U: first the A-image (2 rowtiles x 16 ds x 64 lanes x 8 = 32 KB), then
  // (after hoist) the B double-buffers Bst[2][2 streams][4096 bf16] = 32 KB.
  __shared__ __attribute__((aligned(16))) __bf16 U[16384];
  __shared__ int cand[BM][CAP];                                          // 10 KB
  __shared__ int ccount[BM];
  __shared__ unsigned rowmaxU[BM];                 // running max of e (exp dom)
  __shared__ unsigned long long rowkey[BM];
  __shared__ float esumL[BM], invR[BM], lred[256];
  __shared__ int idxr[BM];

  const int t = threadIdx.x;
  const int lane = t & 63, wv = t >> 6;
  const int ln31 = lane & 31, lh = lane >> 5;
  const int wr = wv >> 1, wc = wv & 1;    // row-tile, column-stream
  const int row0 = blockIdx.x * BM;
  const int ctbase = wc * TPS;

  if (t < BM) {
    ccount[t] = 0; rowmaxU[t] = 0u; rowkey[t] = ~0ULL; esumL[t] = 0.f;
  }

  // ---- stage A (rows 0..63) frag image into U cooperatively ----
  #pragma unroll
  for (int i = 0; i < 8; ++i) {
    int idx = i * 256 + t;            // 2048 units of 16B
    int l = idx & 63, ds = (idx >> 6) & 15, rt = idx >> 10;
    int row = rt * 32 + (l & 31), d0 = ds * 16 + (l >> 5) * 8;
    const float* src = z + (size_t)(row0 + row) * DIM + d0;
    float4 a = *(const float4*)src;
    float4 b = *(const float4*)(src + 4);
    bf8 h;
    h[0] = (__bf16)a.x; h[1] = (__bf16)a.y; h[2] = (__bf16)a.z; h[3] = (__bf16)a.w;
    h[4] = (__bf16)b.x; h[5] = (__bf16)b.y; h[6] = (__bf16)b.z; h[7] = (__bf16)b.w;
    *(bf8*)&U[((size_t)((rt * 16 + ds) * 64 + l)) * 8] = h;
  }
  __syncthreads();

  // ---- hoist A fragments to registers (64 VGPR), then U becomes B buffers ----
  AQ_ALL(AQ_DECL)
  __syncthreads();

  // stage one half (8KB/stream) of B tile ct into buf: this wave issues its
  // 4KB share (4 x global_load_lds); the stream's 2 row-waves cover the half.
  #define STAGEH(ct, h, buf) { \
    const char* g_ = (const char*)frag + (size_t)(ct) * 16384 + (size_t)(h) * 8192 \
                     + wr * 4096 + (size_t)lane * 16; \
    char* l_ = (char*)U + (buf) * 16384 + wc * 8192 + wr * 4096; \
    GLOAD_LDS(g_, l_); \
    GLOAD_LDS(g_ + 1024, l_ + 1024); \
    GLOAD_LDS(g_ + 2048, l_ + 2048); \
    GLOAD_LDS(g_ + 3072, l_ + 3072); \
  }
  #define BSP(buf) ((const __bf16*)((const char*)U + (buf) * 16384 + wc * 8192))

  float es[16];
  #pragma unroll
  for (int i = 0; i < 16; ++i) es[i] = 0.f;

  // ============ Phase 1: prime tile (tt=0) + sweep (tt=1..64) ============
  // Per tile (R7-validated): [stage h1 -> buf1 | consume h0 | barrier |
  //                           stage next h0 -> buf0 | consume h1 | epi | barrier]
  {
    STAGEH(ctbase, 0, 0)
    __syncthreads();
    for (int tt = 0; tt < 65; ++tt) {
      const int ct = ctbase + (tt ? tt - 1 : 0);
      STAGEH(ct, 1, 1)
      f16v acc;
      #pragma unroll
      for (int r = 0; r < 16; ++r) acc[r] = 0.f;
      CONSUME_H0(BSP(0))
      __syncthreads();
      {
        int ctn = ctbase + ((tt < 64) ? tt : 63);   // tile tt+1 (tail: re-stage)
        STAGEH(ctn, 0, 0)
      }
      CONSUME_H1(BSP(1))
      const float cnl = cnorm[ct * 32 + ln31] * L2E;
      if (tt == 0) {
        // prime epilogue: seed shared row max (both streams seed each row)
        #pragma unroll
        for (int r = 0; r < 16; ++r) {
          const int row = wr * 32 + (r & 3) + 8 * (r >> 2) + 4 * lh;
          float e = exp2f(__builtin_fmaf(acc[r], K2L2E, -cnl));
          atomicMax(&rowmaxU[row], __float_as_uint(e));  // e>0: order-preserving
        }
      } else {
        // epilogue-start snapshot of shared row-max (lower bound of true max
        // at any snapshot time -> superset candidate filter, validated logic)
        float cr[16];
        {
          const float4* rmf = (const float4*)(rowmaxU + wr * 32);
          float4 c0 = rmf[lh], c1 = rmf[2 + lh], c2 = rmf[4 + lh], c3 = rmf[6 + lh];
          cr[0]  = c0.x; cr[1]  = c0.y; cr[2]  = c0.z; cr[3]  = c0.w;
          cr[4]  = c1.x; cr[5]  = c1.y; cr[6]  = c1.z; cr[7]  = c1.w;
          cr[8]  = c2.x; cr[9]  = c2.y; cr[10] = c2.z; cr[11] = c2.w;
          cr[12] = c3.x; cr[13] = c3.y; cr[14] = c3.z; cr[15] = c3.w;
        }
        unsigned cond = 0u;
        #pragma unroll
        for (int r = 0; r < 16; ++r) {
          float e = exp2f(__builtin_fmaf(acc[r], K2L2E, -cnl));
          es[r] += e;                       // per-wave sequential fl-chain
          cond |= (e >= cr[r] * KAPPA) ? (1u << r) : 0u;
        }
        if (cond) {   // rare exec-masked slow path: refresh max + insert
          #pragma unroll
          for (int r = 0; r < 16; ++r) {
            if (cond & (1u << r)) {
              const int row = wr * 32 + (r & 3) + 8 * (r >> 2) + 4 * lh;
              float e = exp2f(__builtin_fmaf(acc[r], K2L2E, -cnl));
              atomicMax(&rowmaxU[row], __float_as_uint(e));
              int slot = atomicAdd(&ccount[row], 1);
              if (slot < CAP) cand[row][slot] = ct * 32 + ln31;
            }
          }
        }
      }
      __syncthreads();
    }
  }

  // ---- row exp-sum reduction (32 lanes of same half share rows) ----
  #pragma unroll
  for (int r = 0; r < 16; ++r) {
    float e = es[r];
    #pragma unroll
    for (int off = 16; off > 0; off >>= 1) e += __shfl_xor(e, off);
    if (ln31 == 0) {
      const int row = wr * 32 + (r & 3) + 8 * (r >> 2) + 4 * lh;
      atomicAdd(&esumL[row], e);
    }
  }
  __syncthreads();
  if (t < BM) invR[t] = 1.0f / esumL[t];
  __syncthreads();

  // ---- exact np-bitwise rescore of candidates -> argmin (4 threads/row) ----
  {
    int r = t & 63, q = t >> 6;   // q in 0..3
    int cnt = ccount[r];
    const float* zr = z + (size_t)(row0 + r) * DIM;
    float rn = znorm[row0 + r];
    if (cnt <= CAP) {
      for (int s = q; s < cnt; s += 4) {
        int k = cand[r][s];
        float d2 = exact_d2(zr, cbw + (size_t)k * DIM, rn, cnorm[k]);
        atomicMin(&rowkey[r], (((unsigned long long)ford(d2)) << 32) | (unsigned)k);
      }
    } else {  // overflow (improbable): full exact scan, still correct
      for (int k = q; k < KC; k += 4) {
        float d2 = exact_d2(zr, cbw + (size_t)k * DIM, rn, cnorm[k]);
        atomicMin(&rowkey[r], (((unsigned long long)ford(d2)) << 32) | (unsigned)k);
      }
    }
  }
  __syncthreads();
  if (t < BM) {
    int idx = (int)(rowkey[t] & 0xFFFFFFFFULL);
    idxr[t] = idx;
    out[OUT_IDX + row0 + t] = (float)idx;
  }
  __syncthreads();

  // ---- z_q gather, STE output, loss partial (256 threads = 256 cols) ----
  float lacc = 0.f;
  for (int r = 0; r < BM; ++r) {
    int idx = idxr[r];
    float zq = cbw[(size_t)idx * DIM + t];
    float zv = z[(size_t)(row0 + r) * DIM + t];
    float df = __fsub_rn(zq, zv);
    out[(size_t)(row0 + r) * DIM + t] = __fadd_rn(zv, df);
    lacc += df * df;
  }
  lred[t] = lacc;
  __syncthreads();
  #pragma unroll
  for (int s = 128; s > 0; s >>= 1) {
    if (t < s) lred[t] += lred[t + s];
    __syncthreads();
  }
  if (t == 0) atomicAdd(losssum, (double)lred[0]);

  // ---- invR to regs for phase 2 ----
  float ir[16];
  #pragma unroll
  for (int r = 0; r < 16; ++r)
    ir[r] = invR[wr * 32 + (r & 3) + 8 * (r >> 2) + 4 * lh];
  __syncthreads();

  // ============ Phase 2: avg_probs sweep (tt = 0..63) ============
  {
    float* shadow = avgp8 + (size_t)(blockIdx.x & 7) * KC;
    STAGEH(ctbase, 0, 0)
    __syncthreads();
    for (int tt = 0; tt < 64; ++tt) {
      const int ct = ctbase + tt;
      STAGEH(ct, 1, 1)
      f16v acc;
      #pragma unroll
      for (int r = 0; r < 16; ++r) acc[r] = 0.f;
      CONSUME_H0(BSP(0))
      __syncthreads();
      {
        int ctn = ctbase + ((tt < 63) ? tt + 1 : 63);
        STAGEH(ctn, 0, 0)
      }
      CONSUME_H1(BSP(1))
      const float cnl = cnorm[ct * 32 + ln31] * L2E;
      float s2 = 0.f;
      #pragma unroll
      for (int r = 0; r < 16; ++r) {
        float e = exp2f(__builtin_fmaf(acc[r], K2L2E, -cnl));
        s2 = __builtin_fmaf(e, ir[r], s2);
      }
      s2 += __shfl_xor(s2, 32);           // merge the two lh halves (same col)
      if (lh == 0) atomicAdd(&shadow[ct * 32 + ln31], s2);  // 2 row-waves/col
      __syncthreads();
    }
  }
}

__global__ void k_final(const float* __restrict__ avgp8,
                        const double* __restrict__ losssum,
                        float* __restrict__ out) {
  const int t = threadIdx.x;
  double part = 0.0;
  for (int k = t; k < KC; k += 256) {
    float a4 = 0.f;
    #pragma unroll
    for (int s = 0; s < 8; ++s) a4 += avgp8[s * KC + k];
    double a = (double)a4 / (double)NROWS;
    part += a * log(a + 1e-10);
  }
  __shared__ double sd[256];
  sd[t] = part;
  __syncthreads();
  for (int s = 128; s > 0; s >>= 1) {
    if (t < s) sd[t] += sd[t + s];
    __syncthreads();
  }
  if (t == 0) {
    double H = -sd[0];
    double mse = losssum[0] / (double)((size_t)NROWS * DIM);
    double ccl = 1.25 * mse;
    double sel = -0.1 * H;
    out[OUT_SCAL + 0] = (float)(ccl + sel);
    out[OUT_SCAL + 1] = (float)ccl;
    out[OUT_SCAL + 2] = (float)sel;
  }
}

extern "C" void kernel_launch(void* const* d_in, const int* in_sizes, int n_in,
                              void* d_out, int out_size, void* d_ws, size_t ws_size,
                              hipStream_t stream) {
  const float* z = (const float*)d_in[0];
  const float* cbw = (const float*)d_in[1];
  float* out = (float*)d_out;
  char* ws = (char*)d_ws;
  float* cnorm = (float*)(ws + WS_CNORM);
  float* znorm = (float*)(ws + WS_ZNORM);
  double* losssum = (double*)(ws + WS_LOSS);
  float* avgp8 = (float*)(ws + WS_AVGP8);
  __bf16* frag = (__bf16*)(ws + WS_FRAG);

  hipMemsetAsync(ws + WS_LOSS, 0, 8, stream);
  hipMemsetAsync(ws + WS_AVGP8, 0, 8 * KC * 4, stream);
  k_norms<<<(KC + NROWS) / 256, 256, 0, stream>>>(cbw, z, cnorm, znorm);
  k_frag<<<(KC * 32) / 256, 256, 0, stream>>>(cbw, frag);
  k_main<<<NROWS / BM, 256, 0, stream>>>(z, cbw, cnorm, znorm, frag, out,
                                         avgp8, losssum);
  k_final<<<1, 256, 0, stream>>>(avgp8, losssum, out);
}